// Round 1
// baseline (402.988 us; speedup 1.0000x reference)
//
#include <hip/hip_runtime.h>
#include <math.h>

#define BLOCK 512
#define NWAVES (BLOCK / 64)   // 8 waves/block
#define CAND_CAP 6144         // LDS candidate buffer (24 KB)
#define NREG 12               // wave0 register-resident candidates: 64*12 = 768

__device__ __forceinline__ float waveReduceMax(float v) {
#pragma unroll
    for (int off = 32; off > 0; off >>= 1)
        v = fmaxf(v, __shfl_down(v, off, 64));
    return v;
}
__device__ __forceinline__ float waveReduceSum(float v) {
#pragma unroll
    for (int off = 32; off > 0; off >>= 1)
        v += __shfl_down(v, off, 64);
    return v;
}

// One block per row. Two streaming passes instead of full-row register caching:
//   pass 1: row max (pure stream, ~40 VGPR footprint)
//   pass 2: candidate compaction (x >= rowmax-2 i.e. u=(x-max)/2 >= -1 >= tau*);
//           the 128 KB row is still L2/L3-resident from pass 1.
// launch_bounds(512, 8) => 64-VGPR budget, 8 waves/SIMD => 4 blocks/CU resident
// (vs 1 block/CU before): block A's reduce/solve phases overlap blocks B-D's
// HBM streams, and the wave0-only serial solve no longer idles the CU.
// Solve (unchanged, previously verified): 18 bisection steps on
// f(tau)=sum max(u-tau,0)^2 over candidates (monotone, bracket [-1,0]), then
// exact closed-form tau* = mean - sqrt((1-ss)/k) on the identified support —
// identical to the reference's sorted-cumsum formula.
__global__ __launch_bounds__(BLOCK, 8) void tsallis15_kernel(
    const float* __restrict__ x, const int* __restrict__ tgt,
    float* __restrict__ out, int n, int d, float inv_n)
{
    __shared__ float s_cand[CAND_CAP];
    __shared__ float s_red[NWAVES];
    __shared__ int   s_cnt;
    __shared__ float s_bcast;

    const int row  = blockIdx.x;
    const int t    = threadIdx.x;
    const int lane = t & 63;
    const int wave = t >> 6;
    const float* __restrict__ xr = x + (size_t)row * (size_t)d;
    const float4* __restrict__ xr4 = reinterpret_cast<const float4*>(xr);
    const int d4 = d >> 2;          // float4 count; tail (d&3) handled scalar

    if (t == 0) s_cnt = 0;

    // ---- pass 1: block max (streaming) ----
    float m = -INFINITY;
    for (int i = t; i < d4; i += BLOCK) {
        float4 v = xr4[i];
        m = fmaxf(m, fmaxf(fmaxf(v.x, v.y), fmaxf(v.z, v.w)));
    }
    {   // scalar tail (< 4 elements, single converged step)
        int e = (d4 << 2) + t;
        if (e < d) m = fmaxf(m, xr[e]);
    }
    m = waveReduceMax(m);
    if (lane == 0) s_red[wave] = m;
    __syncthreads();
    if (wave == 0) {
        float v = (lane < NWAVES) ? s_red[lane] : -INFINITY;
        v = waveReduceMax(v);
        if (lane == 0) s_bcast = v;
    }
    __syncthreads();
    const float rowmax = s_bcast;
    const float thr = rowmax - 2.0f;

    // ---- pass 2: candidate filter via per-wave ballot compaction ----
    // Row is hot in L2/L3. Fast path: one ballot per float4 (max-of-4 test);
    // per-element compaction only when some lane in the wave has a hit.
    for (int i = t; i < d4; i += BLOCK) {
        float4 v = xr4[i];
        float mx4 = fmaxf(fmaxf(v.x, v.y), fmaxf(v.z, v.w));
        unsigned long long any = __ballot(mx4 >= thr);
        if (any) {                                   // wave-uniform branch
            float vals[4] = { v.x, v.y, v.z, v.w };
#pragma unroll
            for (int c = 0; c < 4; ++c) {
                float vv = vals[c];
                bool pred = (vv >= thr);
                unsigned long long mask = __ballot(pred);
                if (mask) {
                    int base;
                    if (lane == 0) base = atomicAdd(&s_cnt, __popcll(mask));
                    base = __shfl(base, 0, 64);
                    if (pred) {
                        int pos = base + (int)__popcll(mask & ((1ull << lane) - 1ull));
                        if (pos < CAND_CAP) s_cand[pos] = (vv - rowmax) * 0.5f;
                    }
                }
            }
        }
    }
    {   // scalar tail, single converged step
        int e = (d4 << 2) + t;
        float vv = (e < d) ? xr[e] : -INFINITY;
        bool pred = (vv >= thr);
        unsigned long long mask = __ballot(pred);
        if (mask) {
            int base;
            if (lane == 0) base = atomicAdd(&s_cnt, __popcll(mask));
            base = __shfl(base, 0, 64);
            if (pred) {
                int pos = base + (int)__popcll(mask & ((1ull << lane) - 1ull));
                if (pos < CAND_CAP) s_cand[pos] = (vv - rowmax) * 0.5f;
            }
        }
    }
    __syncthreads();

    // ---- wave 0: register-resident root-find + loss terms ----
    if (wave == 0) {
        const int k = min(s_cnt, CAND_CAP);

        // issue the target-logit load early; consumed only at the very end
        float xt = 0.0f;
        if (lane == 0) xt = xr[tgt[row]];

        float ur[NREG];
#pragma unroll
        for (int j = 0; j < NREG; ++j) {
            int idx = lane + 64 * j;
            ur[j] = (idx < k) ? s_cand[idx] : -1e30f;   // sentinel: never in support
        }

        // bisection: f monotone decreasing, f(-1)>=1>=f(0), tau* in [-1,0]
        float lo = -1.0f, hi = 0.0f;
        for (int it = 0; it < 18; ++it) {
            float tau = 0.5f * (lo + hi);
            float acc = 0.0f;
#pragma unroll
            for (int j = 0; j < NREG; ++j) {
                float u = ur[j] - tau;
                acc += (u > 0.0f) ? u * u : 0.0f;
            }
            for (int j = 64 * NREG + lane; j < k; j += 64) {  // overflow tail (normally 0-trip)
                float u = s_cand[j] - tau;
                if (u > 0.0f) acc += u * u;
            }
            float tot = waveReduceSum(acc);
            tot = __shfl(tot, 0, 64);
            if (tot >= 1.0f) lo = tau; else hi = tau;
        }
        const float tau_b = 0.5f * (lo + hi);

        // exact closed form on identified support: tau* = mean - sqrt((1-ss)/k)
        float s1 = 0.0f, s2 = 0.0f, sc = 0.0f;
#pragma unroll
        for (int j = 0; j < NREG; ++j) {
            float u = ur[j];
            if (u > tau_b) { s1 += u; s2 += u * u; sc += 1.0f; }
        }
        for (int j = 64 * NREG + lane; j < k; j += 64) {
            float u = s_cand[j];
            if (u > tau_b) { s1 += u; s2 += u * u; sc += 1.0f; }
        }
        s1 = waveReduceSum(s1); s1 = __shfl(s1, 0, 64);
        s2 = waveReduceSum(s2); s2 = __shfl(s2, 0, 64);
        sc = waveReduceSum(sc); sc = __shfl(sc, 0, 64);
        float mean  = s1 / sc;
        float ss    = s2 - s1 * mean;              // sum of squared deviations
        float delta = (1.0f - ss) / sc;
        if (delta < 0.0f) delta = 0.0f;
        const float tau_star = mean - sqrtf(delta);

        // loss terms: sum p^{3/2} = sum u^3;  dot(p, x) with x = 2u + rowmax
        float p32 = 0.0f, dot = 0.0f;
#pragma unroll
        for (int j = 0; j < NREG; ++j) {
            float u = ur[j] - tau_star;
            if (u > 0.0f) {
                float p = u * u;
                p32 += p * u;
                dot += p * (2.0f * ur[j] + rowmax);
            }
        }
        for (int j = 64 * NREG + lane; j < k; j += 64) {
            float uc = s_cand[j];
            float u  = uc - tau_star;
            if (u > 0.0f) {
                float p = u * u;
                p32 += p * u;
                dot += p * (2.0f * uc + rowmax);
            }
        }
        p32 = waveReduceSum(p32);
        dot = waveReduceSum(dot);
        if (lane == 0) {
            float loss = (1.0f - p32) * (4.0f / 3.0f) + dot - xt;
            atomicAdd(out, loss * inv_n);
        }
    }
}

extern "C" void kernel_launch(void* const* d_in, const int* in_sizes, int n_in,
                              void* d_out, int out_size, void* d_ws, size_t ws_size,
                              hipStream_t stream) {
    const float* x   = (const float*)d_in[0];
    const int*   tgt = (const int*)d_in[1];
    float*       out = (float*)d_out;

    const int n = in_sizes[1];
    const int d = in_sizes[0] / n;

    hipMemsetAsync(out, 0, (size_t)out_size * sizeof(float), stream);
    tsallis15_kernel<<<n, BLOCK, 0, stream>>>(x, tgt, out, n, d, 1.0f / (float)n);
}

// Round 2
// 384.236 us; speedup vs baseline: 1.0488x; 1.0488x over previous
//
#include <hip/hip_runtime.h>
#include <math.h>

#define BLOCK 512
#define NWAVES (BLOCK / 64)   // 8 waves/block
#define NV 16                 // float4 per thread: 512*16*4 = 32768 >= d
#define CAND_CAP 6144         // LDS candidate buffer (24 KB)
#define NREG 12               // wave0 register-resident candidates: 64*12 = 768

__device__ __forceinline__ float waveReduceMax(float v) {
#pragma unroll
    for (int off = 32; off > 0; off >>= 1)
        v = fmaxf(v, __shfl_down(v, off, 64));
    return v;
}
__device__ __forceinline__ float waveReduceSum(float v) {
#pragma unroll
    for (int off = 32; off > 0; off >>= 1)
        v += __shfl_down(v, off, 64);
    return v;
}

// One block per row; SINGLE HBM pass (row cached in registers: 16 x float4 /
// thread @ 512 threads covers d <= 32768), at 2 blocks/CU.
// launch_bounds(512,4): 8 waves/block, 4 waves/EU min => k = 4*4/8 = 2
// blocks/CU resident, VGPR budget 128 (64 payload + ~35 overhead fits, no
// spill). Rationale (R1 counters): at 1 block/CU the load burst (~5.2us/CU)
// alternates with ~2.5us of barrier/reduce/solve where HBM is idle => 67%
// duty = 4.1 TB/s measured. Two resident blocks overlap block A's compute
// with block B's load burst => ~full HBM duty. The R1 two-pass variant paid
// 2x traffic (pass 2 spilled past L2: 128 rows/XCD * 128KB = 16MB > 4MB) and
// regressed; registers are the only cache that holds the row for free.
// Solve (verified exact, absmax=0): candidates x >= rowmax-2 (u >= -1 >=
// tau*) compacted to LDS via per-wave ballot; wave 0 runs 18 bisection steps
// on f(tau)=sum max(u-tau,0)^2 (monotone, bracket [-1,0]) then the exact
// closed form tau* = mean - sqrt((1-ss)/k) on the identified support --
// identical to the reference's sorted-cumsum formula.
__global__ __launch_bounds__(BLOCK, 4) void tsallis15_kernel(
    const float* __restrict__ x, const int* __restrict__ tgt,
    float* __restrict__ out, int n, int d, float inv_n)
{
    __shared__ float s_cand[CAND_CAP];
    __shared__ float s_red[NWAVES];
    __shared__ int   s_cnt;
    __shared__ float s_bcast;

    const int row  = blockIdx.x;
    const int t    = threadIdx.x;
    const int lane = t & 63;
    const int wave = t >> 6;
    const float* __restrict__ xr = x + (size_t)row * (size_t)d;
    const float4* __restrict__ xr4 = reinterpret_cast<const float4*>(xr);
    const int d4 = d >> 2;            // float4 count
    const int tail0 = d4 << 2;        // first scalar-tail element (d%4 != 0 only)

    if (t == 0) s_cnt = 0;

    // ---- single HBM pass: row -> registers ----
    float4 r[NV];
#pragma unroll
    for (int j = 0; j < NV; ++j) {
        int idx = t + j * BLOCK;
        if (idx < d4) {
            r[j] = xr4[idx];
        } else {
            r[j] = make_float4(-INFINITY, -INFINITY, -INFINITY, -INFINITY);
        }
    }
    float tailv = -INFINITY;          // scalar tail element (rare path)
    if (tail0 + t < d) tailv = xr[tail0 + t];

    // ---- block max ----
    float m = tailv;
#pragma unroll
    for (int j = 0; j < NV; ++j)
        m = fmaxf(m, fmaxf(fmaxf(r[j].x, r[j].y), fmaxf(r[j].z, r[j].w)));
    m = waveReduceMax(m);
    if (lane == 0) s_red[wave] = m;
    __syncthreads();
    if (wave == 0) {
        float v = (lane < NWAVES) ? s_red[lane] : -INFINITY;
        v = waveReduceMax(v);
        if (lane == 0) s_bcast = v;
    }
    __syncthreads();
    const float rowmax = s_bcast;
    const float thr = rowmax - 2.0f;

    // ---- candidate filter via per-wave ballot compaction ----
    // float4-level early-out: one ballot per vec4; per-element ballots only
    // when some lane in the wave has a hit (wave-uniform branch).
#pragma unroll
    for (int j = 0; j < NV; ++j) {
        float4 v = r[j];
        float mx4 = fmaxf(fmaxf(v.x, v.y), fmaxf(v.z, v.w));
        unsigned long long any = __ballot(mx4 >= thr);
        if (any) {
            float vals[4] = { v.x, v.y, v.z, v.w };
#pragma unroll
            for (int c = 0; c < 4; ++c) {
                float vv = vals[c];
                bool pred = (vv >= thr);
                unsigned long long mask = __ballot(pred);
                if (mask) {
                    int base;
                    if (lane == 0) base = atomicAdd(&s_cnt, __popcll(mask));
                    base = __shfl(base, 0, 64);
                    if (pred) {
                        int pos = base + (int)__popcll(mask & ((1ull << lane) - 1ull));
                        if (pos < CAND_CAP) s_cand[pos] = (vv - rowmax) * 0.5f;
                    }
                }
            }
        }
    }
    {   // scalar tail (0-trip when d%4==0; single converged step otherwise)
        bool pred = (tailv >= thr);
        unsigned long long mask = __ballot(pred);
        if (mask) {
            int base;
            if (lane == 0) base = atomicAdd(&s_cnt, __popcll(mask));
            base = __shfl(base, 0, 64);
            if (pred) {
                int pos = base + (int)__popcll(mask & ((1ull << lane) - 1ull));
                if (pos < CAND_CAP) s_cand[pos] = (tailv - rowmax) * 0.5f;
            }
        }
    }
    __syncthreads();

    // ---- wave 0: register-resident root-find + loss terms ----
    // (r[] is dead here; the compiler reuses its registers for ur[].)
    if (wave == 0) {
        const int k = min(s_cnt, CAND_CAP);

        // issue the target-logit load early; consumed only at the very end
        float xt = 0.0f;
        if (lane == 0) xt = xr[tgt[row]];

        float ur[NREG];
#pragma unroll
        for (int j = 0; j < NREG; ++j) {
            int idx = lane + 64 * j;
            ur[j] = (idx < k) ? s_cand[idx] : -1e30f;   // sentinel: never in support
        }

        // bisection: f monotone decreasing, f(-1)>=1>=f(0), tau* in [-1,0]
        float lo = -1.0f, hi = 0.0f;
        for (int it = 0; it < 18; ++it) {
            float tau = 0.5f * (lo + hi);
            float acc = 0.0f;
#pragma unroll
            for (int j = 0; j < NREG; ++j) {
                float u = ur[j] - tau;
                acc += (u > 0.0f) ? u * u : 0.0f;
            }
            for (int j = 64 * NREG + lane; j < k; j += 64) {  // overflow tail (normally 0-trip)
                float u = s_cand[j] - tau;
                if (u > 0.0f) acc += u * u;
            }
            float tot = waveReduceSum(acc);
            tot = __shfl(tot, 0, 64);
            if (tot >= 1.0f) lo = tau; else hi = tau;
        }
        const float tau_b = 0.5f * (lo + hi);

        // exact closed form on identified support: tau* = mean - sqrt((1-ss)/k)
        float s1 = 0.0f, s2 = 0.0f, sc = 0.0f;
#pragma unroll
        for (int j = 0; j < NREG; ++j) {
            float u = ur[j];
            if (u > tau_b) { s1 += u; s2 += u * u; sc += 1.0f; }
        }
        for (int j = 64 * NREG + lane; j < k; j += 64) {
            float u = s_cand[j];
            if (u > tau_b) { s1 += u; s2 += u * u; sc += 1.0f; }
        }
        s1 = waveReduceSum(s1); s1 = __shfl(s1, 0, 64);
        s2 = waveReduceSum(s2); s2 = __shfl(s2, 0, 64);
        sc = waveReduceSum(sc); sc = __shfl(sc, 0, 64);
        float mean  = s1 / sc;
        float ss    = s2 - s1 * mean;              // sum of squared deviations
        float delta = (1.0f - ss) / sc;
        if (delta < 0.0f) delta = 0.0f;
        const float tau_star = mean - sqrtf(delta);

        // loss terms: sum p^{3/2} = sum u^3;  dot(p, x) with x = 2u + rowmax
        float p32 = 0.0f, dot = 0.0f;
#pragma unroll
        for (int j = 0; j < NREG; ++j) {
            float u = ur[j] - tau_star;
            if (u > 0.0f) {
                float p = u * u;
                p32 += p * u;
                dot += p * (2.0f * ur[j] + rowmax);
            }
        }
        for (int j = 64 * NREG + lane; j < k; j += 64) {
            float uc = s_cand[j];
            float u  = uc - tau_star;
            if (u > 0.0f) {
                float p = u * u;
                p32 += p * u;
                dot += p * (2.0f * uc + rowmax);
            }
        }
        p32 = waveReduceSum(p32);
        dot = waveReduceSum(dot);
        if (lane == 0) {
            float loss = (1.0f - p32) * (4.0f / 3.0f) + dot - xt;
            atomicAdd(out, loss * inv_n);
        }
    }
}

extern "C" void kernel_launch(void* const* d_in, const int* in_sizes, int n_in,
                              void* d_out, int out_size, void* d_ws, size_t ws_size,
                              hipStream_t stream) {
    const float* x   = (const float*)d_in[0];
    const int*   tgt = (const int*)d_in[1];
    float*       out = (float*)d_out;

    const int n = in_sizes[1];
    const int d = in_sizes[0] / n;

    hipMemsetAsync(out, 0, (size_t)out_size * sizeof(float), stream);
    tsallis15_kernel<<<n, BLOCK, 0, stream>>>(x, tgt, out, n, d, 1.0f / (float)n);
}